// Round 4
// baseline (268.250 us; speedup 1.0000x reference)
//
#include <hip/hip_runtime.h>
#include <math.h>

#define B_  8
#define R_  64
#define C_  256
#define NH_ 8
#define N_  4096
#define HD_ 32

typedef float fvec4 __attribute__((ext_vector_type(4)));

__device__ __forceinline__ float softplus_rcp(float s) {
    return 1.f / __logf(1.f + __expf(s));     // 1/softplus, fast intrinsics
}

// ---------------------------------------------------------------------------
// Kernel N: per-token norm-rescale scalars only. One wave per token; lane l
// owns channels 4l..4l+3; full-C (256) reductions via wave butterfly.
//   qs[tok] = ||qv|| / ||qv^3||,  ks likewise (qv = (relu+eps)/softplus(sc)).
// Writes 2 floats/token (256 KB total) instead of 67 MB of q3/k3.
// ---------------------------------------------------------------------------
__global__ __launch_bounds__(256) void kernelN(
        const float* __restrict__ qkv, const float* __restrict__ pos,
        const float* __restrict__ scale,
        float* __restrict__ qs_arr, float* __restrict__ ks_arr) {
    const int t    = threadIdx.x;
    const int wave = t >> 6, lane = t & 63;
    const int tok  = blockIdx.x * 4 + wave;
    const int n    = tok & (N_ - 1);
    const int c0   = lane * 4;

    const size_t qidx = (size_t)tok * C_ + c0;
    const float4 q4 = *(const float4*)(qkv + qidx);
    const float4 k4 = *(const float4*)(qkv + (size_t)B_ * N_ * C_ + qidx);
    const float4 p4 = *(const float4*)(pos + (size_t)n * C_ + c0);
    const float4 s4 = *(const float4*)(scale + c0);

    float qa[4] = {q4.x, q4.y, q4.z, q4.w};
    float ka[4] = {k4.x, k4.y, k4.z, k4.w};
    float pa[4] = {p4.x, p4.y, p4.z, p4.w};
    float sa[4] = {s4.x, s4.y, s4.z, s4.w};

    float sq2 = 0.f, sq6 = 0.f, sk2 = 0.f, sk6 = 0.f;
    #pragma unroll
    for (int i = 0; i < 4; i++) {
        const float rsc = softplus_rcp(sa[i]);
        const float qv = (fmaxf(qa[i], 0.f) + 1e-6f) * rsc;
        const float kv = (fmaxf(ka[i] + pa[i], 0.f) + 1e-6f) * rsc;
        sq2 += qv * qv;  sk2 += kv * kv;
        const float q3 = qv * qv * qv, k3 = kv * kv * kv;
        sq6 += q3 * q3;  sk6 += k3 * k3;
    }
    #pragma unroll
    for (int m = 1; m < 64; m <<= 1) {
        sq2 += __shfl_xor(sq2, m, 64);
        sq6 += __shfl_xor(sq6, m, 64);
        sk2 += __shfl_xor(sk2, m, 64);
        sk6 += __shfl_xor(sk6, m, 64);
    }
    if (lane == 0) {
        qs_arr[tok] = sqrtf(sq2) * rsqrtf(sq6);
        ks_arr[tok] = sqrtf(sk2) * rsqrtf(sk6);
    }
}

// ---------------------------------------------------------------------------
// Kernel B2: kv[c][d] = sum_n kfin[n][c]*v[n][d], ksum[c] = sum_n kfin[n][c],
// with kfin = ((relu(k+pos)+eps)*rsc)^3 * ks[n] computed on the fly during
// LDS staging (no kf intermediate). 64 heads x 8 n-chunks, atomicAdd epilogue.
// ---------------------------------------------------------------------------
__global__ __launch_bounds__(256) void kernelB2(
        const float* __restrict__ qkv, const float* __restrict__ pos,
        const float* __restrict__ scale, const float* __restrict__ ks_arr,
        float* __restrict__ kv_ws, float* __restrict__ ksum_ws) {
    __shared__ float k_s[128 * HD_];
    __shared__ float v_s[128 * HD_];
    __shared__ float rsc_s[HD_];
    const int t     = threadIdx.x;
    const int bh    = blockIdx.x >> 3;
    const int chunk = blockIdx.x & 7;
    const int b     = bh >> 3, h = bh & 7;
    const int c     = t >> 3, p = t & 7, dbase = p * 4;

    if (t < HD_) rsc_s[t] = softplus_rcp(scale[h * HD_ + t]);
    __syncthreads();

    float a0 = 0.f, a1 = 0.f, a2 = 0.f, a3 = 0.f, ksp = 0.f;
    const size_t kbase = (size_t)B_ * N_ * C_ + (size_t)b * N_ * C_ + h * HD_;
    const size_t vbase = (size_t)2 * B_ * N_ * C_ + (size_t)b * N_ * C_ + h * HD_;
    const int tokbase = b * N_;

    for (int tile = 0; tile < 4; tile++) {
        const int n0 = chunk * 512 + tile * 128;
        #pragma unroll
        for (int i = 0; i < 4; i++) {
            const int j  = (i * 256 + t) * 4;
            const int nl = j >> 5, d = j & 31;
            const float4 kr = *(const float4*)(qkv + kbase + (size_t)(n0 + nl) * C_ + d);
            const float4 pr = *(const float4*)(pos + (size_t)(n0 + nl) * C_ + h * HD_ + d);
            const float ksn = ks_arr[tokbase + n0 + nl];
            float4 o;
            {
                float v0 = (fmaxf(kr.x + pr.x, 0.f) + 1e-6f) * rsc_s[d + 0];
                float v1 = (fmaxf(kr.y + pr.y, 0.f) + 1e-6f) * rsc_s[d + 1];
                float v2 = (fmaxf(kr.z + pr.z, 0.f) + 1e-6f) * rsc_s[d + 2];
                float v3 = (fmaxf(kr.w + pr.w, 0.f) + 1e-6f) * rsc_s[d + 3];
                o.x = v0 * v0 * v0 * ksn;  o.y = v1 * v1 * v1 * ksn;
                o.z = v2 * v2 * v2 * ksn;  o.w = v3 * v3 * v3 * ksn;
            }
            *(float4*)&k_s[j] = o;
            ((float4*)v_s)[i * 256 + t] =
                *(const float4*)(qkv + vbase + (size_t)(n0 + nl) * C_ + d);
        }
        __syncthreads();
        #pragma unroll 4
        for (int nl = 0; nl < 128; nl++) {
            const float  kc = k_s[nl * HD_ + c];
            const float4 vv = *(const float4*)&v_s[nl * HD_ + dbase];
            a0 = fmaf(kc, vv.x, a0);
            a1 = fmaf(kc, vv.y, a1);
            a2 = fmaf(kc, vv.z, a2);
            a3 = fmaf(kc, vv.w, a3);
        }
        #pragma unroll
        for (int i = 0; i < 16; i++)
            ksp += k_s[(p + i * 8) * HD_ + c];
        __syncthreads();
    }
    float* kvdst = kv_ws + (size_t)bh * 1024 + c * HD_ + dbase;
    atomicAdd(kvdst + 0, a0);
    atomicAdd(kvdst + 1, a1);
    atomicAdd(kvdst + 2, a2);
    atomicAdd(kvdst + 3, a3);
    k_s[c * 8 + p] = ksp;
    __syncthreads();
    if (t < 32) {
        float s = 0.f;
        #pragma unroll
        for (int i = 0; i < 8; i++) s += k_s[t * 8 + i];
        atomicAdd(&ksum_ws[bh * HD_ + t], s);
    }
}

// ---------------------------------------------------------------------------
// Kernel CD2: fused attention epilogue + both depthwise convs; out written
// ONCE (nontemporal). Block = 16x16 px tile x 1 head. q-feature recomputed
// on the fly from raw q + qs[tok] (no qf intermediate).
// ---------------------------------------------------------------------------
__global__ __launch_bounds__(256) void kernelCD2(
        const float* __restrict__ qkv, const float* __restrict__ qs_arr,
        const float* __restrict__ kv_ws, const float* __restrict__ ksum_ws,
        const float* __restrict__ scale,
        const float* __restrict__ w_v,  const float* __restrict__ b_v,
        const float* __restrict__ w_dwc, const float* __restrict__ b_dwc,
        float* __restrict__ out) {
    __shared__ float v_s[20 * 20 * 32];   // 51.2 KB; reused as conv_s (256*33)
    __shared__ float kv_s[1024];
    __shared__ float ks_s[32];
    __shared__ float rsc_s[32];
    const int t    = threadIdx.x;
    const int tile = blockIdx.x;
    const int h    = blockIdx.y;
    const int b    = blockIdx.z;
    const int ty0  = (tile >> 2) * 16, tx0 = (tile & 3) * 16;
    const int bh   = b * NH_ + h;

    ((float4*)kv_s)[t] = ((const float4*)(kv_ws + (size_t)bh * 1024))[t];
    if (t < 32) {
        ks_s[t]  = ksum_ws[bh * HD_ + t];
        rsc_s[t] = softplus_rcp(scale[h * HD_ + t]);
    }

    const float* vb = qkv + (size_t)2 * B_ * N_ * C_ + (size_t)b * N_ * C_ + h * HD_;
    #pragma unroll
    for (int i = 0; i < 13; i++) {
        const int idx = i * 256 + t;
        if (idx < 3200) {
            const int pix = idx >> 3, d4 = (idx & 7) * 4;
            const int yy = pix / 20, xx = pix - yy * 20;
            const int gy = ty0 + yy - 2, gx = tx0 + xx - 2;
            float4 val = make_float4(0.f, 0.f, 0.f, 0.f);
            if (gy >= 0 && gy < R_ && gx >= 0 && gx < R_)
                val = *(const float4*)(vb + (size_t)(gy * R_ + gx) * C_ + d4);
            *(float4*)&v_s[pix * 32 + d4] = val;
        }
    }

    const int c  = t & 31, pg = t >> 5;
    float wv[9], wd[25];
    {
        const float* wvp = w_v + (size_t)(h * HD_ + c) * 9;
        const float* wdp = w_dwc + (size_t)c * 25;
        #pragma unroll
        for (int i = 0; i < 9; i++)  wv[i] = wvp[i];
        #pragma unroll
        for (int i = 0; i < 25; i++) wd[i] = wdp[i];
    }
    const float bias = b_v[h * HD_ + c] + b_dwc[c];
    __syncthreads();

    // ---- conv phase: thread = (channel c, 2 tile rows), ring window ----
    float res[32];
    #pragma unroll
    for (int r2 = 0; r2 < 2; r2++) {
        const int ty = pg * 2 + r2;
        float win[5][5];
        #pragma unroll
        for (int j = 0; j < 5; j++)
            #pragma unroll
            for (int i = 0; i < 5; i++)
                win[j][i] = v_s[((ty + i) * 20 + j) * 32 + c];
        #pragma unroll
        for (int tx = 0; tx < 16; tx++) {
            float a = bias;
            #pragma unroll
            for (int j = 0; j < 5; j++) {
                const int slot = (tx + j) % 5;
                #pragma unroll
                for (int i = 0; i < 5; i++)
                    a = fmaf(wd[i * 5 + j], win[slot][i], a);
            }
            #pragma unroll
            for (int j = 1; j < 4; j++) {
                const int slot = (tx + j) % 5;
                #pragma unroll
                for (int i = 1; i < 4; i++)
                    a = fmaf(wv[(i - 1) * 3 + (j - 1)], win[slot][i], a);
            }
            res[r2 * 16 + tx] = a;
            if (tx < 15) {
                const int slot = tx % 5;
                #pragma unroll
                for (int i = 0; i < 5; i++)
                    win[slot][i] = v_s[((ty + i) * 20 + (tx + 5)) * 32 + c];
            }
        }
    }
    __syncthreads();
    #pragma unroll
    for (int r2 = 0; r2 < 2; r2++)
        #pragma unroll
        for (int tx = 0; tx < 16; tx++)
            v_s[((pg * 2 + r2) * 16 + tx) * 33 + c] = res[r2 * 16 + tx];
    __syncthreads();

    // ---- attention phase: thread = pixel; q-feature recomputed on the fly ----
    {
        const int tyy = t >> 4, txx = t & 15;
        const int n   = (ty0 + tyy) * R_ + (tx0 + txx);
        const int tok = b * N_ + n;
        float q[32];
        const float4* qsrc = (const float4*)(qkv + (size_t)tok * C_ + h * HD_);
        #pragma unroll
        for (int i = 0; i < 8; i++) ((float4*)q)[i] = qsrc[i];
        const float qs = qs_arr[tok];
        #pragma unroll
        for (int i = 0; i < 32; i++) {
            const float r = (fmaxf(q[i], 0.f) + 1e-6f) * rsc_s[i];
            q[i] = r * r * r * qs;
        }

        float denom = 1e-6f;
        #pragma unroll
        for (int cc = 0; cc < 32; cc++) denom = fmaf(q[cc], ks_s[cc], denom);
        const float z = 1.f / denom;

        float o[32];
        #pragma unroll
        for (int i = 0; i < 32; i++) o[i] = 0.f;
        #pragma unroll
        for (int cc = 0; cc < 32; cc++) {
            const float qc = q[cc];
            #pragma unroll
            for (int d = 0; d < 32; d++)
                o[d] = fmaf(qc, kv_s[cc * 32 + d], o[d]);
        }
        fvec4* dst = (fvec4*)(out + (size_t)tok * C_ + h * HD_);
        #pragma unroll
        for (int i = 0; i < 8; i++) {
            fvec4 v4;
            v4.x = fmaf(o[i*4+0], z, v_s[t * 33 + i*4+0]);
            v4.y = fmaf(o[i*4+1], z, v_s[t * 33 + i*4+1]);
            v4.z = fmaf(o[i*4+2], z, v_s[t * 33 + i*4+2]);
            v4.w = fmaf(o[i*4+3], z, v_s[t * 33 + i*4+3]);
            __builtin_nontemporal_store(v4, dst + i);
        }
    }
}

// ---------------------------------------------------------------------------
extern "C" void kernel_launch(void* const* d_in, const int* in_sizes, int n_in,
                              void* d_out, int out_size, void* d_ws, size_t ws_size,
                              hipStream_t stream) {
    const float* qkv   = (const float*)d_in[0];
    const float* pos   = (const float*)d_in[1];
    const float* scale = (const float*)d_in[2];
    const float* w_v   = (const float*)d_in[3];
    const float* b_v   = (const float*)d_in[4];
    const float* w_dwc = (const float*)d_in[5];
    const float* b_dwc = (const float*)d_in[6];
    float* out = (float*)d_out;

    float* qs_arr  = (float*)d_ws;                   // B*N floats
    float* ks_arr  = qs_arr + (size_t)B_ * N_;       // B*N floats
    float* kv_ws   = ks_arr + (size_t)B_ * N_;       // 64*1024 floats
    float* ksum_ws = kv_ws + 64 * 1024;              // 64*32 floats

    (void)hipMemsetAsync(kv_ws, 0, (64 * 1024 + 64 * 32) * sizeof(float), stream);
    kernelN<<<dim3(B_ * N_ / 4), 256, 0, stream>>>(qkv, pos, scale, qs_arr, ks_arr);
    kernelB2<<<dim3(512), 256, 0, stream>>>(qkv, pos, scale, ks_arr, kv_ws, ksum_ws);
    kernelCD2<<<dim3(16, NH_, B_), 256, 0, stream>>>(qkv, qs_arr, kv_ws, ksum_ws,
                                                     scale, w_v, b_v, w_dwc, b_dwc, out);
}

// Round 5
// 222.778 us; speedup vs baseline: 1.2041x; 1.2041x over previous
//
#include <hip/hip_runtime.h>
#include <math.h>

#define B_  8
#define R_  64
#define C_  256
#define NH_ 8
#define N_  4096
#define HD_ 32

__device__ __forceinline__ float softplus_rcp(float s) {
    return 1.f / __logf(1.f + __expf(s));     // 1/softplus, fast intrinsics
}

// ---------------------------------------------------------------------------
// Kernel N: per-token norm-rescale scalars only. One wave per token; lane l
// owns channels 4l..4l+3; full-C (256) reductions via wave butterfly.
//   qs[tok] = ||qv|| / ||qv^3||,  ks likewise (qv = (relu+eps)/softplus(sc)).
// ---------------------------------------------------------------------------
__global__ __launch_bounds__(256) void kernelN(
        const float* __restrict__ qkv, const float* __restrict__ pos,
        const float* __restrict__ scale,
        float* __restrict__ qs_arr, float* __restrict__ ks_arr) {
    const int t    = threadIdx.x;
    const int wave = t >> 6, lane = t & 63;
    const int tok  = blockIdx.x * 4 + wave;
    const int n    = tok & (N_ - 1);
    const int c0   = lane * 4;

    const size_t qidx = (size_t)tok * C_ + c0;
    const float4 q4 = *(const float4*)(qkv + qidx);
    const float4 k4 = *(const float4*)(qkv + (size_t)B_ * N_ * C_ + qidx);
    const float4 p4 = *(const float4*)(pos + (size_t)n * C_ + c0);
    const float4 s4 = *(const float4*)(scale + c0);

    float qa[4] = {q4.x, q4.y, q4.z, q4.w};
    float ka[4] = {k4.x, k4.y, k4.z, k4.w};
    float pa[4] = {p4.x, p4.y, p4.z, p4.w};
    float sa[4] = {s4.x, s4.y, s4.z, s4.w};

    float sq2 = 0.f, sq6 = 0.f, sk2 = 0.f, sk6 = 0.f;
    #pragma unroll
    for (int i = 0; i < 4; i++) {
        const float rsc = softplus_rcp(sa[i]);
        const float qv = (fmaxf(qa[i], 0.f) + 1e-6f) * rsc;
        const float kv = (fmaxf(ka[i] + pa[i], 0.f) + 1e-6f) * rsc;
        sq2 += qv * qv;  sk2 += kv * kv;
        const float q3 = qv * qv * qv, k3 = kv * kv * kv;
        sq6 += q3 * q3;  sk6 += k3 * k3;
    }
    #pragma unroll
    for (int m = 1; m < 64; m <<= 1) {
        sq2 += __shfl_xor(sq2, m, 64);
        sq6 += __shfl_xor(sq6, m, 64);
        sk2 += __shfl_xor(sk2, m, 64);
        sk6 += __shfl_xor(sk6, m, 64);
    }
    if (lane == 0) {
        qs_arr[tok] = sqrtf(sq2) * rsqrtf(sq6);
        ks_arr[tok] = sqrtf(sk2) * rsqrtf(sk6);
    }
}

// ---------------------------------------------------------------------------
// Kernel B2: kv[c][d] = sum_n kfin[n][c]*v[n][d], ksum[c] = sum_n kfin[n][c],
// with kfin = ((relu(k+pos)+eps)*rsc)^3 * ks[n] computed on the fly during
// LDS staging (no kf intermediate). 64 heads x 8 n-chunks, atomicAdd epilogue.
// ---------------------------------------------------------------------------
__global__ __launch_bounds__(256) void kernelB2(
        const float* __restrict__ qkv, const float* __restrict__ pos,
        const float* __restrict__ scale, const float* __restrict__ ks_arr,
        float* __restrict__ kv_ws, float* __restrict__ ksum_ws) {
    __shared__ float k_s[128 * HD_];
    __shared__ float v_s[128 * HD_];
    __shared__ float rsc_s[HD_];
    const int t     = threadIdx.x;
    const int bh    = blockIdx.x >> 3;
    const int chunk = blockIdx.x & 7;
    const int b     = bh >> 3, h = bh & 7;
    const int c     = t >> 3, p = t & 7, dbase = p * 4;

    if (t < HD_) rsc_s[t] = softplus_rcp(scale[h * HD_ + t]);
    __syncthreads();

    float a0 = 0.f, a1 = 0.f, a2 = 0.f, a3 = 0.f, ksp = 0.f;
    const size_t kbase = (size_t)B_ * N_ * C_ + (size_t)b * N_ * C_ + h * HD_;
    const size_t vbase = (size_t)2 * B_ * N_ * C_ + (size_t)b * N_ * C_ + h * HD_;
    const int tokbase = b * N_;

    for (int tile = 0; tile < 4; tile++) {
        const int n0 = chunk * 512 + tile * 128;
        #pragma unroll
        for (int i = 0; i < 4; i++) {
            const int j  = (i * 256 + t) * 4;
            const int nl = j >> 5, d = j & 31;
            const float4 kr = *(const float4*)(qkv + kbase + (size_t)(n0 + nl) * C_ + d);
            const float4 pr = *(const float4*)(pos + (size_t)(n0 + nl) * C_ + h * HD_ + d);
            const float ksn = ks_arr[tokbase + n0 + nl];
            float4 o;
            {
                float v0 = (fmaxf(kr.x + pr.x, 0.f) + 1e-6f) * rsc_s[d + 0];
                float v1 = (fmaxf(kr.y + pr.y, 0.f) + 1e-6f) * rsc_s[d + 1];
                float v2 = (fmaxf(kr.z + pr.z, 0.f) + 1e-6f) * rsc_s[d + 2];
                float v3 = (fmaxf(kr.w + pr.w, 0.f) + 1e-6f) * rsc_s[d + 3];
                o.x = v0 * v0 * v0 * ksn;  o.y = v1 * v1 * v1 * ksn;
                o.z = v2 * v2 * v2 * ksn;  o.w = v3 * v3 * v3 * ksn;
            }
            *(float4*)&k_s[j] = o;
            ((float4*)v_s)[i * 256 + t] =
                *(const float4*)(qkv + vbase + (size_t)(n0 + nl) * C_ + d);
        }
        __syncthreads();
        #pragma unroll 4
        for (int nl = 0; nl < 128; nl++) {
            const float  kc = k_s[nl * HD_ + c];
            const float4 vv = *(const float4*)&v_s[nl * HD_ + dbase];
            a0 = fmaf(kc, vv.x, a0);
            a1 = fmaf(kc, vv.y, a1);
            a2 = fmaf(kc, vv.z, a2);
            a3 = fmaf(kc, vv.w, a3);
        }
        #pragma unroll
        for (int i = 0; i < 16; i++)
            ksp += k_s[(p + i * 8) * HD_ + c];
        __syncthreads();
    }
    float* kvdst = kv_ws + (size_t)bh * 1024 + c * HD_ + dbase;
    atomicAdd(kvdst + 0, a0);
    atomicAdd(kvdst + 1, a1);
    atomicAdd(kvdst + 2, a2);
    atomicAdd(kvdst + 3, a3);
    k_s[c * 8 + p] = ksp;
    __syncthreads();
    if (t < 32) {
        float s = 0.f;
        #pragma unroll
        for (int i = 0; i < 8; i++) s += k_s[t * 8 + i];
        atomicAdd(&ksum_ws[bh * HD_ + t], s);
    }
}

// ---------------------------------------------------------------------------
// Kernel CD2: fused attention epilogue + both depthwise convs; out written
// ONCE via plain float4 stores (each lane covers a full 128B line across its
// 8 stores -> L2 write-combines to full-line HBM writes; nontemporal here
// caused 4x write amplification in R4).
// ---------------------------------------------------------------------------
__global__ __launch_bounds__(256) void kernelCD2(
        const float* __restrict__ qkv, const float* __restrict__ qs_arr,
        const float* __restrict__ kv_ws, const float* __restrict__ ksum_ws,
        const float* __restrict__ scale,
        const float* __restrict__ w_v,  const float* __restrict__ b_v,
        const float* __restrict__ w_dwc, const float* __restrict__ b_dwc,
        float* __restrict__ out) {
    __shared__ float v_s[20 * 20 * 32];   // 51.2 KB; reused as conv_s (256*33)
    __shared__ float kv_s[1024];
    __shared__ float ks_s[32];
    __shared__ float rsc_s[32];
    const int t    = threadIdx.x;
    const int tile = blockIdx.x;
    const int h    = blockIdx.y;
    const int b    = blockIdx.z;
    const int ty0  = (tile >> 2) * 16, tx0 = (tile & 3) * 16;
    const int bh   = b * NH_ + h;

    ((float4*)kv_s)[t] = ((const float4*)(kv_ws + (size_t)bh * 1024))[t];
    if (t < 32) {
        ks_s[t]  = ksum_ws[bh * HD_ + t];
        rsc_s[t] = softplus_rcp(scale[h * HD_ + t]);
    }

    const float* vb = qkv + (size_t)2 * B_ * N_ * C_ + (size_t)b * N_ * C_ + h * HD_;
    #pragma unroll
    for (int i = 0; i < 13; i++) {
        const int idx = i * 256 + t;
        if (idx < 3200) {
            const int pix = idx >> 3, d4 = (idx & 7) * 4;
            const int yy = pix / 20, xx = pix - yy * 20;
            const int gy = ty0 + yy - 2, gx = tx0 + xx - 2;
            float4 val = make_float4(0.f, 0.f, 0.f, 0.f);
            if (gy >= 0 && gy < R_ && gx >= 0 && gx < R_)
                val = *(const float4*)(vb + (size_t)(gy * R_ + gx) * C_ + d4);
            *(float4*)&v_s[pix * 32 + d4] = val;
        }
    }

    const int c  = t & 31, pg = t >> 5;
    float wv[9], wd[25];
    {
        const float* wvp = w_v + (size_t)(h * HD_ + c) * 9;
        const float* wdp = w_dwc + (size_t)c * 25;
        #pragma unroll
        for (int i = 0; i < 9; i++)  wv[i] = wvp[i];
        #pragma unroll
        for (int i = 0; i < 25; i++) wd[i] = wdp[i];
    }
    const float bias = b_v[h * HD_ + c] + b_dwc[c];
    __syncthreads();

    // ---- conv phase: thread = (channel c, 2 tile rows), ring window ----
    float res[32];
    #pragma unroll
    for (int r2 = 0; r2 < 2; r2++) {
        const int ty = pg * 2 + r2;
        float win[5][5];
        #pragma unroll
        for (int j = 0; j < 5; j++)
            #pragma unroll
            for (int i = 0; i < 5; i++)
                win[j][i] = v_s[((ty + i) * 20 + j) * 32 + c];
        #pragma unroll
        for (int tx = 0; tx < 16; tx++) {
            float a = bias;
            #pragma unroll
            for (int j = 0; j < 5; j++) {
                const int slot = (tx + j) % 5;
                #pragma unroll
                for (int i = 0; i < 5; i++)
                    a = fmaf(wd[i * 5 + j], win[slot][i], a);
            }
            #pragma unroll
            for (int j = 1; j < 4; j++) {
                const int slot = (tx + j) % 5;
                #pragma unroll
                for (int i = 1; i < 4; i++)
                    a = fmaf(wv[(i - 1) * 3 + (j - 1)], win[slot][i], a);
            }
            res[r2 * 16 + tx] = a;
            if (tx < 15) {
                const int slot = tx % 5;
                #pragma unroll
                for (int i = 0; i < 5; i++)
                    win[slot][i] = v_s[((ty + i) * 20 + (tx + 5)) * 32 + c];
            }
        }
    }
    __syncthreads();
    #pragma unroll
    for (int r2 = 0; r2 < 2; r2++)
        #pragma unroll
        for (int tx = 0; tx < 16; tx++)
            v_s[((pg * 2 + r2) * 16 + tx) * 33 + c] = res[r2 * 16 + tx];
    __syncthreads();

    // ---- attention phase: thread = pixel; q-feature recomputed on the fly ----
    {
        const int tyy = t >> 4, txx = t & 15;
        const int n   = (ty0 + tyy) * R_ + (tx0 + txx);
        const int tok = b * N_ + n;
        float q[32];
        const float4* qsrc = (const float4*)(qkv + (size_t)tok * C_ + h * HD_);
        #pragma unroll
        for (int i = 0; i < 8; i++) ((float4*)q)[i] = qsrc[i];
        const float qs = qs_arr[tok];
        #pragma unroll
        for (int i = 0; i < 32; i++) {
            const float r = (fmaxf(q[i], 0.f) + 1e-6f) * rsc_s[i];
            q[i] = r * r * r * qs;
        }

        float denom = 1e-6f;
        #pragma unroll
        for (int cc = 0; cc < 32; cc++) denom = fmaf(q[cc], ks_s[cc], denom);
        const float z = 1.f / denom;

        float o[32];
        #pragma unroll
        for (int i = 0; i < 32; i++) o[i] = 0.f;
        #pragma unroll
        for (int cc = 0; cc < 32; cc++) {
            const float qc = q[cc];
            #pragma unroll
            for (int d = 0; d < 32; d++)
                o[d] = fmaf(qc, kv_s[cc * 32 + d], o[d]);
        }
        float4* dst = (float4*)(out + (size_t)tok * C_ + h * HD_);
        #pragma unroll
        for (int i = 0; i < 8; i++) {
            float4 v4;
            v4.x = fmaf(o[i*4+0], z, v_s[t * 33 + i*4+0]);
            v4.y = fmaf(o[i*4+1], z, v_s[t * 33 + i*4+1]);
            v4.z = fmaf(o[i*4+2], z, v_s[t * 33 + i*4+2]);
            v4.w = fmaf(o[i*4+3], z, v_s[t * 33 + i*4+3]);
            dst[i] = v4;
        }
    }
}

// ---------------------------------------------------------------------------
extern "C" void kernel_launch(void* const* d_in, const int* in_sizes, int n_in,
                              void* d_out, int out_size, void* d_ws, size_t ws_size,
                              hipStream_t stream) {
    const float* qkv   = (const float*)d_in[0];
    const float* pos   = (const float*)d_in[1];
    const float* scale = (const float*)d_in[2];
    const float* w_v   = (const float*)d_in[3];
    const float* b_v   = (const float*)d_in[4];
    const float* w_dwc = (const float*)d_in[5];
    const float* b_dwc = (const float*)d_in[6];
    float* out = (float*)d_out;

    float* qs_arr  = (float*)d_ws;                   // B*N floats
    float* ks_arr  = qs_arr + (size_t)B_ * N_;       // B*N floats
    float* kv_ws   = ks_arr + (size_t)B_ * N_;       // 64*1024 floats
    float* ksum_ws = kv_ws + 64 * 1024;              // 64*32 floats

    (void)hipMemsetAsync(kv_ws, 0, (64 * 1024 + 64 * 32) * sizeof(float), stream);
    kernelN<<<dim3(B_ * N_ / 4), 256, 0, stream>>>(qkv, pos, scale, qs_arr, ks_arr);
    kernelB2<<<dim3(512), 256, 0, stream>>>(qkv, pos, scale, ks_arr, kv_ws, ksum_ws);
    kernelCD2<<<dim3(16, NH_, B_), 256, 0, stream>>>(qkv, qs_arr, kv_ws, ksum_ws,
                                                     scale, w_v, b_v, w_dwc, b_dwc, out);
}